// Round 1
// baseline (22594.348 us; speedup 1.0000x reference)
//
#include <hip/hip_runtime.h>
#include <math.h>

// NeuralODE: sequential RK4 orbit propagation with J2-J5 gravity + tiny MLP
// correction. Latency-bound: single wave (64 lanes), whole time loop in-kernel.
// lane = tid&31 owns hidden neuron `lane`; upper half mirrors lower half.

namespace {
constexpr double dMU = 398600.4418;
constexpr double dRE = 6378.137;
constexpr double dJ2 = 0.00108262668;
constexpr double dJ3 = -2.53265648e-06;
constexpr double dJ4 = -1.61962159e-06;
constexpr double dJ5 = -2.27296082e-07;

constexpr float MU_F = (float)dMU;
constexpr float C2_F = (float)(-1.5 * dJ2 * dMU * dRE * dRE);
constexpr float C3_F = (float)(-2.5 * dJ3 * dMU * dRE * dRE * dRE);
constexpr float C4_F = (float)(15.0 / 8.0 * dJ4 * dMU * dRE * dRE * dRE * dRE);
constexpr float C5_F = (float)(3.0 / 8.0 * dJ5 * dMU * dRE * dRE * dRE * dRE * dRE);
constexpr float D5_F = (float)(-(15.0 / 8.0) * dJ5 * dMU * dRE * dRE * dRE * dRE * dRE);
constexpr float IRREF = (float)(1.0 / 7000.0);
constexpr float IVREF = (float)(1.0 / 7.5);
constexpr float AREF  = (float)(7.5 * 7.5 / 7000.0);
} // namespace

__device__ __forceinline__ float fast_tanh(float x) {
    // tanh(x) = 1 - 2/(exp(2x)+1); exp(2x) = exp2(2*log2(e)*x)
    float e = __builtin_amdgcn_exp2f(x * 2.8853900817779268f);
    return 1.0f - 2.0f * __builtin_amdgcn_rcpf(e + 1.0f);
}

__global__ void __launch_bounds__(64, 1)
node_kernel(const float* __restrict__ state0,
            const float* __restrict__ W1, const float* __restrict__ b1,
            const float* __restrict__ W2, const float* __restrict__ b2,
            const float* __restrict__ W3, const float* __restrict__ b3,
            const float* __restrict__ plog_scale,
            const int*  __restrict__ pdt,
            float* __restrict__ out, int M)
{
    __shared__ __align__(16) float sh[32];
    const int lane = (int)(threadIdx.x & 31u);

    // dt arrives as a 1-element array; sniff int32 vs float32 bit pattern.
    int db = *pdt;
    float dtf = (db >= 1 && db <= 1000000) ? (float)db : __int_as_float(db);
    const float half_dt  = 0.5f * dtf;
    const float sixth_dt = dtf * (1.0f / 6.0f);

    const float scale =
        __builtin_amdgcn_exp2f(plog_scale[0] * 1.4426950408889634f) * AREF;

    // Per-lane weights in registers.
    float w1r[6];
    #pragma unroll
    for (int k = 0; k < 6; ++k) w1r[k] = W1[lane * 6 + k];
    const float b1r = b1[lane];
    float w2r[32];
    #pragma unroll
    for (int i = 0; i < 32; ++i) w2r[i] = W2[lane * 32 + i];
    const float b2r = b2[lane];
    const float w30 = W3[lane], w31 = W3[32 + lane], w32 = W3[64 + lane];
    const float b30 = b3[0], b31 = b3[1], b32 = b3[2];

    float st[6];
    #pragma unroll
    for (int j = 0; j < 6; ++j) st[j] = state0[j];

    // dynamics: (pos, vel) -> acceleration (uniform across lanes on return)
    auto dyn = [&](float px, float py, float pz, float vx, float vy, float vz,
                   float& ax, float& ay, float& az) {
        // --- J2..J5 gravity (uniform scalar math on every lane) ---
        float r2  = fmaf(px, px, fmaf(py, py, pz * pz));
        float ir  = __builtin_amdgcn_rsqf(r2);
        float ir2 = ir * ir;
        float ir3 = ir2 * ir;
        float ir5 = ir3 * ir2;
        float ir7 = ir5 * ir2;
        float ir9 = ir7 * ir2;
        float z2  = pz * pz;
        float zr2 = z2 * ir2;
        float zr4 = zr2 * zr2;

        float gmr3 = -MU_F * ir3;
        float gx = gmr3 * px, gy = gmr3 * py, gz = gmr3 * pz;

        float c2 = C2_F * ir5;
        float q2 = fmaf(-5.0f, zr2, 1.0f);
        gx = fmaf(c2 * px, q2, gx);
        gy = fmaf(c2 * py, q2, gy);
        gz = fmaf(c2 * pz, fmaf(-5.0f, zr2, 3.0f), gz);

        float c3 = C3_F * ir7;
        float t3 = pz * fmaf(-7.0f, zr2, 3.0f);
        gx = fmaf(c3 * px, t3, gx);
        gy = fmaf(c3 * py, t3, gy);
        gz = fmaf(c3, fmaf(z2, fmaf(-7.0f, zr2, 6.0f), -0.6f * r2), gz);

        float c4 = C4_F * ir7;
        float p4 = fmaf(21.0f, zr4, fmaf(-14.0f, zr2, 1.0f));
        gx = fmaf(c4 * px, p4, gx);
        gy = fmaf(c4 * py, p4, gy);
        float p4z = fmaf(21.0f, zr4, fmaf(-23.333333333333332f, zr2, 5.0f));
        gz = fmaf(c4 * pz, p4z, gz);

        float c5 = C5_F * ir9;
        float p5 = fmaf(231.0f, zr4, fmaf(-210.0f, zr2, 35.0f));
        float c5z = c5 * pz;
        gx = fmaf(c5z * px, p5, gx);
        gy = fmaf(c5z * py, p5, gy);
        float p5z = fmaf(231.0f, zr4, fmaf(-315.0f, zr2, 105.0f));
        gz = fmaf(c5 * z2, p5z, gz);
        gz = fmaf(D5_F, ir7, gz);

        // --- MLP layer 1: lane owns neuron `lane` ---
        float pre = b1r;
        pre = fmaf(w1r[0], px * IRREF, pre);
        pre = fmaf(w1r[1], py * IRREF, pre);
        pre = fmaf(w1r[2], pz * IRREF, pre);
        pre = fmaf(w1r[3], vx * IVREF, pre);
        pre = fmaf(w1r[4], vy * IVREF, pre);
        pre = fmaf(w1r[5], vz * IVREF, pre);
        float h1 = fast_tanh(pre);

        // Broadcast h1 via LDS. Single wave => lockstep; the compiler orders
        // the dependent reads after the write with s_waitcnt lgkmcnt.
        sh[lane] = h1;
        const float4* shv = (const float4*)sh;
        float a0 = b2r, a1 = 0.0f, a2 = 0.0f, a3 = 0.0f;
        #pragma unroll
        for (int i = 0; i < 8; ++i) {
            float4 h = shv[i];
            a0 = fmaf(w2r[4 * i + 0], h.x, a0);
            a1 = fmaf(w2r[4 * i + 1], h.y, a1);
            a2 = fmaf(w2r[4 * i + 2], h.z, a2);
            a3 = fmaf(w2r[4 * i + 3], h.w, a3);
        }
        float h2 = fast_tanh((a0 + a1) + (a2 + a3));

        // --- layer 3: per-lane partials + 32-lane butterfly (both halves
        // mirror, masks <=16 stay within each half) ---
        float p0 = w30 * h2, p1 = w31 * h2, p2 = w32 * h2;
        #pragma unroll
        for (int mk = 1; mk <= 16; mk <<= 1) {
            p0 += __shfl_xor(p0, mk);
            p1 += __shfl_xor(p1, mk);
            p2 += __shfl_xor(p2, mk);
        }
        ax = fmaf(scale, p0 + b30, gx);
        ay = fmaf(scale, p1 + b31, gy);
        az = fmaf(scale, p2 + b32, gz);
    };

    for (int m = 0; m < M; ++m) {
        float k1[6], k2[6], k3[6], k4[6], t[6];

        k1[0] = st[3]; k1[1] = st[4]; k1[2] = st[5];
        dyn(st[0], st[1], st[2], st[3], st[4], st[5], k1[3], k1[4], k1[5]);

        #pragma unroll
        for (int j = 0; j < 6; ++j) t[j] = fmaf(half_dt, k1[j], st[j]);
        k2[0] = t[3]; k2[1] = t[4]; k2[2] = t[5];
        dyn(t[0], t[1], t[2], t[3], t[4], t[5], k2[3], k2[4], k2[5]);

        #pragma unroll
        for (int j = 0; j < 6; ++j) t[j] = fmaf(half_dt, k2[j], st[j]);
        k3[0] = t[3]; k3[1] = t[4]; k3[2] = t[5];
        dyn(t[0], t[1], t[2], t[3], t[4], t[5], k3[3], k3[4], k3[5]);

        #pragma unroll
        for (int j = 0; j < 6; ++j) t[j] = fmaf(dtf, k3[j], st[j]);
        k4[0] = t[3]; k4[1] = t[4]; k4[2] = t[5];
        dyn(t[0], t[1], t[2], t[3], t[4], t[5], k4[3], k4[4], k4[5]);

        #pragma unroll
        for (int j = 0; j < 6; ++j) {
            float ksum = k1[j] + 2.0f * (k2[j] + k3[j]) + k4[j];
            st[j] = fmaf(sixth_dt, ksum, st[j]);
        }

        if (threadIdx.x == 0) {
            float2* o = (float2*)(out + (size_t)m * 6);
            o[0] = make_float2(st[0], st[1]);
            o[1] = make_float2(st[2], st[3]);
            o[2] = make_float2(st[4], st[5]);
        }
    }
}

extern "C" void kernel_launch(void* const* d_in, const int* in_sizes, int n_in,
                              void* d_out, int out_size, void* d_ws, size_t ws_size,
                              hipStream_t stream) {
    const float* state0 = (const float*)d_in[0];
    // d_in[1] = eval_times (only its length matters)
    const float* W1 = (const float*)d_in[2];
    const float* b1 = (const float*)d_in[3];
    const float* W2 = (const float*)d_in[4];
    const float* b2 = (const float*)d_in[5];
    const float* W3 = (const float*)d_in[6];
    const float* b3 = (const float*)d_in[7];
    const float* ls = (const float*)d_in[8];
    // d_in[9] = t0 (unused)
    const int* pdt  = (const int*)d_in[10];
    const int M = in_sizes[1];

    node_kernel<<<dim3(1), dim3(64), 0, stream>>>(
        state0, W1, b1, W2, b2, W3, b3, ls, pdt, (float*)d_out, M);
}

// Round 2
// 16163.499 us; speedup vs baseline: 1.3979x; 1.3979x over previous
//
#include <hip/hip_runtime.h>
#include <math.h>

// NeuralODE: sequential RK4 orbit propagation with J2-J5 gravity + tiny MLP
// correction. Latency-bound: single wave (64 lanes), whole time loop in-kernel.
// lane = tid&31 owns hidden neuron `lane`; upper half mirrors lower half.
// R2 change: layer-3 cross-lane reduction via DPP (VALU pipe, ~60cy) instead
// of __shfl_xor butterfly (LDS pipe, ~650cy).

namespace {
constexpr double dMU = 398600.4418;
constexpr double dRE = 6378.137;
constexpr double dJ2 = 0.00108262668;
constexpr double dJ3 = -2.53265648e-06;
constexpr double dJ4 = -1.61962159e-06;
constexpr double dJ5 = -2.27296082e-07;

constexpr float MU_F = (float)dMU;
constexpr float C2_F = (float)(-1.5 * dJ2 * dMU * dRE * dRE);
constexpr float C3_F = (float)(-2.5 * dJ3 * dMU * dRE * dRE * dRE);
constexpr float C4_F = (float)(15.0 / 8.0 * dJ4 * dMU * dRE * dRE * dRE * dRE);
constexpr float C5_F = (float)(3.0 / 8.0 * dJ5 * dMU * dRE * dRE * dRE * dRE * dRE);
constexpr float D5_F = (float)(-(15.0 / 8.0) * dJ5 * dMU * dRE * dRE * dRE * dRE * dRE);
constexpr float IRREF = (float)(1.0 / 7000.0);
constexpr float IVREF = (float)(1.0 / 7.5);
constexpr float AREF  = (float)(7.5 * 7.5 / 7000.0);
} // namespace

__device__ __forceinline__ float fast_tanh(float x) {
    // tanh(x) = 1 - 2/(exp(2x)+1); exp(2x) = exp2(2*log2(e)*x)
    float e = __builtin_amdgcn_exp2f(x * 2.8853900817779268f);
    return 1.0f - 2.0f * __builtin_amdgcn_rcpf(e + 1.0f);
}

// One DPP-permute + add step. CTRL/ROW/BANK are immediates.
template <int CTRL, int ROW, int BANK, bool BC>
__device__ __forceinline__ float dpp_add_step(float x) {
    int p = __builtin_amdgcn_update_dpp(0, __float_as_int(x), CTRL, ROW, BANK, BC);
    return x + __int_as_float(p);
}

// Full 64-lane sum -> uniform SGPR value (returned on every lane).
// Sequence: row prefix sums (row_shr 1,2,4,8), then row_bcast:15 (rows 1,3),
// row_bcast:31 (rows 2,3); lane 63 holds the total; readlane broadcasts.
__device__ __forceinline__ float wave64_sum(float x) {
    x = dpp_add_step<0x111, 0xf, 0xf, true>(x);  // row_shr:1
    x = dpp_add_step<0x112, 0xf, 0xf, true>(x);  // row_shr:2
    x = dpp_add_step<0x114, 0xf, 0xf, true>(x);  // row_shr:4
    x = dpp_add_step<0x118, 0xf, 0xf, true>(x);  // row_shr:8
    x = dpp_add_step<0x142, 0xa, 0xf, true>(x);  // row_bcast:15 -> rows 1,3
    x = dpp_add_step<0x143, 0xc, 0xf, true>(x);  // row_bcast:31 -> rows 2,3
    return __int_as_float(__builtin_amdgcn_readlane(__float_as_int(x), 63));
}

__global__ void __launch_bounds__(64, 1)
node_kernel(const float* __restrict__ state0,
            const float* __restrict__ W1, const float* __restrict__ b1,
            const float* __restrict__ W2, const float* __restrict__ b2,
            const float* __restrict__ W3, const float* __restrict__ b3,
            const float* __restrict__ plog_scale,
            const int*  __restrict__ pdt,
            float* __restrict__ out, int M)
{
    __shared__ __align__(16) float sh[32];
    const int lane = (int)(threadIdx.x & 31u);

    // dt arrives as a 1-element array; sniff int32 vs float32 bit pattern.
    int db = *pdt;
    float dtf = (db >= 1 && db <= 1000000) ? (float)db : __int_as_float(db);
    const float half_dt  = 0.5f * dtf;
    const float sixth_dt = dtf * (1.0f / 6.0f);

    const float scale =
        __builtin_amdgcn_exp2f(plog_scale[0] * 1.4426950408889634f) * AREF;
    const float scaleH = 0.5f * scale;  // 64-lane sum double-counts mirrored halves
    const float sb0 = scale * b3[0], sb1 = scale * b3[1], sb2 = scale * b3[2];

    // Per-lane weights in registers; fold the 1/R_REF, 1/V_REF normalization
    // into the W1 rows so sn never needs to be materialized.
    float w1r[6];
    #pragma unroll
    for (int k = 0; k < 3; ++k) w1r[k] = W1[lane * 6 + k] * IRREF;
    #pragma unroll
    for (int k = 3; k < 6; ++k) w1r[k] = W1[lane * 6 + k] * IVREF;
    const float b1r = b1[lane];
    float w2r[32];
    #pragma unroll
    for (int i = 0; i < 32; ++i) w2r[i] = W2[lane * 32 + i];
    const float b2r = b2[lane];
    const float w30 = W3[lane], w31 = W3[32 + lane], w32 = W3[64 + lane];

    float st[6];
    #pragma unroll
    for (int j = 0; j < 6; ++j) st[j] = state0[j];

    // dynamics: (pos, vel) -> acceleration (uniform across lanes on return)
    auto dyn = [&](float px, float py, float pz, float vx, float vy, float vz,
                   float& ax, float& ay, float& az) {
        // --- MLP layer 1 first so the LDS broadcast can start early and the
        // write->read turnaround hides under the gravity VALU work below. ---
        float pre = b1r;
        pre = fmaf(w1r[0], px, pre);
        pre = fmaf(w1r[1], py, pre);
        pre = fmaf(w1r[2], pz, pre);
        pre = fmaf(w1r[3], vx, pre);
        pre = fmaf(w1r[4], vy, pre);
        pre = fmaf(w1r[5], vz, pre);
        float h1 = fast_tanh(pre);
        sh[lane] = h1;  // single wave => lockstep; compiler orders via lgkmcnt

        // --- J2..J5 gravity (uniform scalar math on every lane) ---
        float r2  = fmaf(px, px, fmaf(py, py, pz * pz));
        float ir  = __builtin_amdgcn_rsqf(r2);
        float ir2 = ir * ir;
        float ir3 = ir2 * ir;
        float ir5 = ir3 * ir2;
        float ir7 = ir5 * ir2;
        float ir9 = ir7 * ir2;
        float z2  = pz * pz;
        float zr2 = z2 * ir2;
        float zr4 = zr2 * zr2;

        float gmr3 = -MU_F * ir3;
        float gx = gmr3 * px, gy = gmr3 * py, gz = gmr3 * pz;

        float c2 = C2_F * ir5;
        float q2 = fmaf(-5.0f, zr2, 1.0f);
        gx = fmaf(c2 * px, q2, gx);
        gy = fmaf(c2 * py, q2, gy);
        gz = fmaf(c2 * pz, fmaf(-5.0f, zr2, 3.0f), gz);

        float c3 = C3_F * ir7;
        float t3 = pz * fmaf(-7.0f, zr2, 3.0f);
        gx = fmaf(c3 * px, t3, gx);
        gy = fmaf(c3 * py, t3, gy);
        gz = fmaf(c3, fmaf(z2, fmaf(-7.0f, zr2, 6.0f), -0.6f * r2), gz);

        float c4 = C4_F * ir7;
        float p4 = fmaf(21.0f, zr4, fmaf(-14.0f, zr2, 1.0f));
        gx = fmaf(c4 * px, p4, gx);
        gy = fmaf(c4 * py, p4, gy);
        float p4z = fmaf(21.0f, zr4, fmaf(-23.333333333333332f, zr2, 5.0f));
        gz = fmaf(c4 * pz, p4z, gz);

        float c5 = C5_F * ir9;
        float p5 = fmaf(231.0f, zr4, fmaf(-210.0f, zr2, 35.0f));
        float c5z = c5 * pz;
        gx = fmaf(c5z * px, p5, gx);
        gy = fmaf(c5z * py, p5, gy);
        float p5z = fmaf(231.0f, zr4, fmaf(-315.0f, zr2, 105.0f));
        gz = fmaf(c5 * z2, p5z, gz);
        gz = fmaf(D5_F, ir7, gz);

        // --- MLP layer 2: broadcast h1 via LDS, each lane owns one neuron ---
        const float4* shv = (const float4*)sh;
        float a0 = b2r, a1 = 0.0f, a2 = 0.0f, a3 = 0.0f;
        #pragma unroll
        for (int i = 0; i < 8; ++i) {
            float4 h = shv[i];
            a0 = fmaf(w2r[4 * i + 0], h.x, a0);
            a1 = fmaf(w2r[4 * i + 1], h.y, a1);
            a2 = fmaf(w2r[4 * i + 2], h.z, a2);
            a3 = fmaf(w2r[4 * i + 3], h.w, a3);
        }
        float h2 = fast_tanh((a0 + a1) + (a2 + a3));

        // --- layer 3: per-lane partials + DPP 64-lane reduction (VALU pipe).
        // Mirrored halves => 64-lane sum = 2x the 32-neuron sum; scaleH folds
        // in the 0.5. Result is SGPR-uniform via readlane. ---
        float s0 = wave64_sum(w30 * h2);
        float s1 = wave64_sum(w31 * h2);
        float s2 = wave64_sum(w32 * h2);
        ax = fmaf(scaleH, s0, gx + sb0);
        ay = fmaf(scaleH, s1, gy + sb1);
        az = fmaf(scaleH, s2, gz + sb2);
    };

    for (int m = 0; m < M; ++m) {
        float k1[6], k2[6], k3[6], k4[6], t[6];

        k1[0] = st[3]; k1[1] = st[4]; k1[2] = st[5];
        dyn(st[0], st[1], st[2], st[3], st[4], st[5], k1[3], k1[4], k1[5]);

        #pragma unroll
        for (int j = 0; j < 6; ++j) t[j] = fmaf(half_dt, k1[j], st[j]);
        k2[0] = t[3]; k2[1] = t[4]; k2[2] = t[5];
        dyn(t[0], t[1], t[2], t[3], t[4], t[5], k2[3], k2[4], k2[5]);

        #pragma unroll
        for (int j = 0; j < 6; ++j) t[j] = fmaf(half_dt, k2[j], st[j]);
        k3[0] = t[3]; k3[1] = t[4]; k3[2] = t[5];
        dyn(t[0], t[1], t[2], t[3], t[4], t[5], k3[3], k3[4], k3[5]);

        #pragma unroll
        for (int j = 0; j < 6; ++j) t[j] = fmaf(dtf, k3[j], st[j]);
        k4[0] = t[3]; k4[1] = t[4]; k4[2] = t[5];
        dyn(t[0], t[1], t[2], t[3], t[4], t[5], k4[3], k4[4], k4[5]);

        #pragma unroll
        for (int j = 0; j < 6; ++j) {
            float ksum = k1[j] + 2.0f * (k2[j] + k3[j]) + k4[j];
            st[j] = fmaf(sixth_dt, ksum, st[j]);
        }

        if (threadIdx.x == 0) {
            float2* o = (float2*)(out + (size_t)m * 6);
            o[0] = make_float2(st[0], st[1]);
            o[1] = make_float2(st[2], st[3]);
            o[2] = make_float2(st[4], st[5]);
        }
    }
}

extern "C" void kernel_launch(void* const* d_in, const int* in_sizes, int n_in,
                              void* d_out, int out_size, void* d_ws, size_t ws_size,
                              hipStream_t stream) {
    const float* state0 = (const float*)d_in[0];
    // d_in[1] = eval_times (only its length matters)
    const float* W1 = (const float*)d_in[2];
    const float* b1 = (const float*)d_in[3];
    const float* W2 = (const float*)d_in[4];
    const float* b2 = (const float*)d_in[5];
    const float* W3 = (const float*)d_in[6];
    const float* b3 = (const float*)d_in[7];
    const float* ls = (const float*)d_in[8];
    // d_in[9] = t0 (unused)
    const int* pdt  = (const int*)d_in[10];
    const int M = in_sizes[1];

    node_kernel<<<dim3(1), dim3(64), 0, stream>>>(
        state0, W1, b1, W2, b2, W3, b3, ls, pdt, (float*)d_out, M);
}

// Round 3
// 13191.597 us; speedup vs baseline: 1.7128x; 1.2253x over previous
//
#include <hip/hip_runtime.h>
#include <math.h>

// NeuralODE: sequential RK4 orbit propagation with J2-J5 gravity + tiny MLP
// correction. Latency-bound: single wave (64 lanes), whole time loop in-kernel.
// lane owns hidden neuron nrn = (tid&31) ^ ((tid>>5)<<4)  (upper half is
// ROW-SWAPPED, not mirrored, so the 16-rows hold partial-sums {A,B,B,A} and a
// single permlane32_swap self-sum yields the full 32-sum on every lane).
// R3 changes: (1) L3 reduce = 4x dpp row_ror adds + permlane32 self-sum
// (no readlane, no SGPR hazard); (2) h1 broadcast via 32x v_readlane into
// SGPRs instead of LDS roundtrip (no lgkmcnt latency; LDS removed).

namespace {
constexpr double dMU = 398600.4418;
constexpr double dRE = 6378.137;
constexpr double dJ2 = 0.00108262668;
constexpr double dJ3 = -2.53265648e-06;
constexpr double dJ4 = -1.61962159e-06;
constexpr double dJ5 = -2.27296082e-07;

constexpr float MU_F = (float)dMU;
constexpr float C2_F = (float)(-1.5 * dJ2 * dMU * dRE * dRE);
constexpr float C3_F = (float)(-2.5 * dJ3 * dMU * dRE * dRE * dRE);
constexpr float C4_F = (float)(15.0 / 8.0 * dJ4 * dMU * dRE * dRE * dRE * dRE);
constexpr float C5_F = (float)(3.0 / 8.0 * dJ5 * dMU * dRE * dRE * dRE * dRE * dRE);
constexpr float D5_F = (float)(-(15.0 / 8.0) * dJ5 * dMU * dRE * dRE * dRE * dRE * dRE);
constexpr float IRREF = (float)(1.0 / 7000.0);
constexpr float IVREF = (float)(1.0 / 7.5);
constexpr float AREF  = (float)(7.5 * 7.5 / 7000.0);
} // namespace

__device__ __forceinline__ float fast_tanh(float x) {
    // tanh(x) = 1 - 2/(exp(2x)+1); exp(2x) = exp2(2*log2(e)*x)
    float e = __builtin_amdgcn_exp2f(x * 2.8853900817779268f);
    return 1.0f - 2.0f * __builtin_amdgcn_rcpf(e + 1.0f);
}

// x += rotate_within_row(x) ; CTRL = 0x120+N (row_ror:N)
template <int CTRL>
__device__ __forceinline__ float dpp_ror_add(float x) {
    int p = __builtin_amdgcn_update_dpp(0, __float_as_int(x), CTRL, 0xf, 0xf, true);
    return x + __int_as_float(p);
}

// Sum of the 32 per-neuron partials -> identical value on all 64 lanes.
// Requires the {A,B,B,A} row layout (nrn mapping above). 4 rotate-adds give
// each lane its 16-row sum; permlane32 self-swap gives {hi,hi},{lo,lo} in
// either hardware orientation, so a+b = rowsum(lane) + rowsum(lane^32) = A+B.
__device__ __forceinline__ float reduce32_all(float p) {
    p = dpp_ror_add<0x121>(p);  // row_ror:1
    p = dpp_ror_add<0x122>(p);  // row_ror:2
    p = dpp_ror_add<0x124>(p);  // row_ror:4
    p = dpp_ror_add<0x128>(p);  // row_ror:8
    int a = __float_as_int(p), b = __float_as_int(p);
    asm("s_nop 0\n\tv_permlane32_swap_b32 %0, %1\n\ts_nop 0"
        : "+v"(a), "+v"(b));
    return __int_as_float(a) + __int_as_float(b);
}

__global__ void __launch_bounds__(64, 1)
node_kernel(const float* __restrict__ state0,
            const float* __restrict__ W1, const float* __restrict__ b1,
            const float* __restrict__ W2, const float* __restrict__ b2,
            const float* __restrict__ W3, const float* __restrict__ b3,
            const float* __restrict__ plog_scale,
            const int*  __restrict__ pdt,
            float* __restrict__ out, int M)
{
    const int tid = (int)threadIdx.x;
    const int nrn = (tid & 31) ^ ((tid >> 5) << 4);  // row-swapped upper half

    // dt arrives as a 1-element array; sniff int32 vs float32 bit pattern.
    int db = *pdt;
    float dtf = (db >= 1 && db <= 1000000) ? (float)db : __int_as_float(db);
    const float half_dt  = 0.5f * dtf;
    const float sixth_dt = dtf * (1.0f / 6.0f);

    const float scale =
        __builtin_amdgcn_exp2f(plog_scale[0] * 1.4426950408889634f) * AREF;
    const float sb0 = scale * b3[0], sb1 = scale * b3[1], sb2 = scale * b3[2];

    // Per-lane weights in registers; fold 1/R_REF, 1/V_REF into W1 rows.
    float w1r[6];
    #pragma unroll
    for (int k = 0; k < 3; ++k) w1r[k] = W1[nrn * 6 + k] * IRREF;
    #pragma unroll
    for (int k = 3; k < 6; ++k) w1r[k] = W1[nrn * 6 + k] * IVREF;
    const float b1r = b1[nrn];
    float w2r[32];
    #pragma unroll
    for (int i = 0; i < 32; ++i) w2r[i] = W2[nrn * 32 + i];
    const float b2r = b2[nrn];
    const float w30 = W3[nrn], w31 = W3[32 + nrn], w32 = W3[64 + nrn];

    float st[6];
    #pragma unroll
    for (int j = 0; j < 6; ++j) st[j] = state0[j];

    // dynamics: (pos, vel) -> acceleration (uniform across lanes on return)
    auto dyn = [&](float px, float py, float pz, float vx, float vy, float vz,
                   float& ax, float& ay, float& az) {
        // --- MLP layer 1: lane owns neuron nrn ---
        float pre = b1r;
        pre = fmaf(w1r[0], px, pre);
        pre = fmaf(w1r[1], py, pre);
        pre = fmaf(w1r[2], pz, pre);
        pre = fmaf(w1r[3], vx, pre);
        pre = fmaf(w1r[4], vy, pre);
        pre = fmaf(w1r[5], vz, pre);
        float h1 = fast_tanh(pre);

        // --- J2..J5 gravity (uniform scalar math; overlaps tanh/readlanes) ---
        float r2  = fmaf(px, px, fmaf(py, py, pz * pz));
        float ir  = __builtin_amdgcn_rsqf(r2);
        float ir2 = ir * ir;
        float ir3 = ir2 * ir;
        float ir5 = ir3 * ir2;
        float ir7 = ir5 * ir2;
        float ir9 = ir7 * ir2;
        float z2  = pz * pz;
        float zr2 = z2 * ir2;
        float zr4 = zr2 * zr2;

        float gmr3 = -MU_F * ir3;
        float gx = gmr3 * px, gy = gmr3 * py, gz = gmr3 * pz;

        float c2 = C2_F * ir5;
        float q2 = fmaf(-5.0f, zr2, 1.0f);
        gx = fmaf(c2 * px, q2, gx);
        gy = fmaf(c2 * py, q2, gy);
        gz = fmaf(c2 * pz, fmaf(-5.0f, zr2, 3.0f), gz);

        float c3 = C3_F * ir7;
        float t3 = pz * fmaf(-7.0f, zr2, 3.0f);
        gx = fmaf(c3 * px, t3, gx);
        gy = fmaf(c3 * py, t3, gy);
        gz = fmaf(c3, fmaf(z2, fmaf(-7.0f, zr2, 6.0f), -0.6f * r2), gz);

        float c4 = C4_F * ir7;
        float p4 = fmaf(21.0f, zr4, fmaf(-14.0f, zr2, 1.0f));
        gx = fmaf(c4 * px, p4, gx);
        gy = fmaf(c4 * py, p4, gy);
        float p4z = fmaf(21.0f, zr4, fmaf(-23.333333333333332f, zr2, 5.0f));
        gz = fmaf(c4 * pz, p4z, gz);

        float c5 = C5_F * ir9;
        float p5 = fmaf(231.0f, zr4, fmaf(-210.0f, zr2, 35.0f));
        float c5z = c5 * pz;
        gx = fmaf(c5z * px, p5, gx);
        gy = fmaf(c5z * py, p5, gy);
        float p5z = fmaf(231.0f, zr4, fmaf(-315.0f, zr2, 105.0f));
        gz = fmaf(c5 * z2, p5z, gz);
        gz = fmaf(D5_F, ir7, gz);

        // --- h1 broadcast: lanes 0..31 hold h1[0..31] (nrn==lane there).
        // v_readlane -> SGPRs; FMAs read them as uniform scalar operands.
        // 31-instruction distance absorbs the VALU-write-SGPR hazard. ---
        float hs[32];
        #pragma unroll
        for (int i = 0; i < 32; ++i)
            hs[i] = __int_as_float(__builtin_amdgcn_readlane(__float_as_int(h1), i));

        // --- MLP layer 2: each lane = neuron nrn, 4 accumulator chains ---
        float a0 = b2r, a1 = 0.0f, a2 = 0.0f, a3 = 0.0f;
        #pragma unroll
        for (int i = 0; i < 8; ++i) {
            a0 = fmaf(w2r[4 * i + 0], hs[4 * i + 0], a0);
            a1 = fmaf(w2r[4 * i + 1], hs[4 * i + 1], a1);
            a2 = fmaf(w2r[4 * i + 2], hs[4 * i + 2], a2);
            a3 = fmaf(w2r[4 * i + 3], hs[4 * i + 3], a3);
        }
        float h2 = fast_tanh((a0 + a1) + (a2 + a3));

        // --- layer 3: per-lane partial + all-lanes 32-sum (VALU only) ---
        float s0 = reduce32_all(w30 * h2);
        float s1 = reduce32_all(w31 * h2);
        float s2 = reduce32_all(w32 * h2);
        ax = fmaf(scale, s0, gx + sb0);
        ay = fmaf(scale, s1, gy + sb1);
        az = fmaf(scale, s2, gz + sb2);
    };

    for (int m = 0; m < M; ++m) {
        float k1[6], k2[6], k3[6], k4[6], t[6];

        k1[0] = st[3]; k1[1] = st[4]; k1[2] = st[5];
        dyn(st[0], st[1], st[2], st[3], st[4], st[5], k1[3], k1[4], k1[5]);

        #pragma unroll
        for (int j = 0; j < 6; ++j) t[j] = fmaf(half_dt, k1[j], st[j]);
        k2[0] = t[3]; k2[1] = t[4]; k2[2] = t[5];
        dyn(t[0], t[1], t[2], t[3], t[4], t[5], k2[3], k2[4], k2[5]);

        #pragma unroll
        for (int j = 0; j < 6; ++j) t[j] = fmaf(half_dt, k2[j], st[j]);
        k3[0] = t[3]; k3[1] = t[4]; k3[2] = t[5];
        dyn(t[0], t[1], t[2], t[3], t[4], t[5], k3[3], k3[4], k3[5]);

        #pragma unroll
        for (int j = 0; j < 6; ++j) t[j] = fmaf(dtf, k3[j], st[j]);
        k4[0] = t[3]; k4[1] = t[4]; k4[2] = t[5];
        dyn(t[0], t[1], t[2], t[3], t[4], t[5], k4[3], k4[4], k4[5]);

        #pragma unroll
        for (int j = 0; j < 6; ++j) {
            float ksum = k1[j] + 2.0f * (k2[j] + k3[j]) + k4[j];
            st[j] = fmaf(sixth_dt, ksum, st[j]);
        }

        if (tid == 0) {
            float2* o = (float2*)(out + (size_t)m * 6);
            o[0] = make_float2(st[0], st[1]);
            o[1] = make_float2(st[2], st[3]);
            o[2] = make_float2(st[4], st[5]);
        }
    }
}

extern "C" void kernel_launch(void* const* d_in, const int* in_sizes, int n_in,
                              void* d_out, int out_size, void* d_ws, size_t ws_size,
                              hipStream_t stream) {
    const float* state0 = (const float*)d_in[0];
    // d_in[1] = eval_times (only its length matters)
    const float* W1 = (const float*)d_in[2];
    const float* b1 = (const float*)d_in[3];
    const float* W2 = (const float*)d_in[4];
    const float* b2 = (const float*)d_in[5];
    const float* W3 = (const float*)d_in[6];
    const float* b3 = (const float*)d_in[7];
    const float* ls = (const float*)d_in[8];
    // d_in[9] = t0 (unused)
    const int* pdt  = (const int*)d_in[10];
    const int M = in_sizes[1];

    node_kernel<<<dim3(1), dim3(64), 0, stream>>>(
        state0, W1, b1, W2, b2, W3, b3, ls, pdt, (float*)d_out, M);
}